// Round 3
// baseline (317.745 us; speedup 1.0000x reference)
//
#include <hip/hip_runtime.h>

// AttentionSampling: out[b,s,:] = q[b,s,:] + sum_f dot(LN(q)[b,s,:], LN(k)[b,4s+f,:]) * LN(v)[b,4s+f,:]
// B=4, Sq=2048, Skv=8192, D=1024, fp32.
//
// R7: R4/R5/R6 all plateaued at ~115-120us. Root cause (consistent across all
// three): ~1-2 outstanding loads per wave. R6's register version had VGPR=120,
// i.e. the RA sank every load to its use to cut pressure -> serial load chain at
// HBM latency (36 loads x ~800ns ~= 29us per row-wave, /8-way overlap = 115us).
// Fix: force the batch. Issue all 36 dwordx4 loads of a row, then pin EVERY
// loaded value as an input to volatile asm (loads cannot sink below a use of
// their result), then sched_barrier(0) so compute cannot interleave upward.
// 36KB in flight per wave x 8 waves/CU >> ~9KB/CU Little's-law requirement.
// Math identical to R6 (passed): expanded dot(qn,kn), one DPP reduction round,
// no LDS, no barriers.

typedef float f32x4 __attribute__((ext_vector_type(4)));

constexpr int D     = 1024;
constexpr int BLOCK = 256;
constexpr int NW    = BLOCK / 64;   // waves per block
constexpr int NRW   = 4;            // rows per wave
constexpr float EPS = 1e-5f;

template<int CTRL>
__device__ __forceinline__ float dpp_add(float x) {
    int xi = __builtin_bit_cast(int, x);
    int yi = __builtin_amdgcn_update_dpp(0, xi, CTRL, 0xF, 0xF, true);
    return x + __builtin_bit_cast(float, yi);
}

// Full wave64 sum on the VALU pipe; broadcast via readlane (SGPR). No LDS, no barrier.
__device__ __forceinline__ float wave_sum(float x) {
    x = dpp_add<0x111>(x);   // row_shr:1
    x = dpp_add<0x112>(x);   // row_shr:2
    x = dpp_add<0x114>(x);   // row_shr:4
    x = dpp_add<0x118>(x);   // row_shr:8
    x = dpp_add<0x142>(x);   // row_bcast:15
    x = dpp_add<0x143>(x);   // row_bcast:31 -> lane 63 holds wave sum
    return __builtin_bit_cast(float, __builtin_amdgcn_readlane(__builtin_bit_cast(int, x), 63));
}

__device__ __forceinline__ f32x4 vadd(f32x4 a, f32x4 b) {
    f32x4 r;
#pragma unroll
    for (int j = 0; j < 4; j++) r[j] = a[j] + b[j];
    return r;
}
__device__ __forceinline__ f32x4 vmul(f32x4 a, f32x4 b) {
    f32x4 r;
#pragma unroll
    for (int j = 0; j < 4; j++) r[j] = a[j] * b[j];
    return r;
}
__device__ __forceinline__ f32x4 vfma(f32x4 a, f32x4 b, f32x4 c) {
    f32x4 r;
#pragma unroll
    for (int j = 0; j < 4; j++) r[j] = fmaf(a[j], b[j], c[j]);
    return r;
}
__device__ __forceinline__ f32x4 vfma_ss(f32x4 a, float s, float c) {
    f32x4 r;
#pragma unroll
    for (int j = 0; j < 4; j++) r[j] = fmaf(a[j], s, c);
    return r;
}
__device__ __forceinline__ f32x4 vfma_sv(float s, f32x4 b, f32x4 c) {
    f32x4 r;
#pragma unroll
    for (int j = 0; j < 4; j++) r[j] = fmaf(s, b[j], c[j]);
    return r;
}
__device__ __forceinline__ float hsum(f32x4 a) { return (a[0] + a[1]) + (a[2] + a[3]); }

// Pin a loaded value set: volatile asm consuming the registers. Loads feeding
// these operands cannot be sunk below this point by the scheduler or RA.
#define PIN4(A)  asm volatile("" :: "v"(A[0]), "v"(A[1]), "v"(A[2]), "v"(A[3]))
#define PIN16(A) asm volatile("" :: \
    "v"(A[0][0]), "v"(A[0][1]), "v"(A[0][2]), "v"(A[0][3]), \
    "v"(A[1][0]), "v"(A[1][1]), "v"(A[1][2]), "v"(A[1][3]), \
    "v"(A[2][0]), "v"(A[2][1]), "v"(A[2][2]), "v"(A[2][3]), \
    "v"(A[3][0]), "v"(A[3][1]), "v"(A[3][2]), "v"(A[3][3]))

__global__ __launch_bounds__(BLOCK, 2) void attn_ds_kernel(
    const float* __restrict__ q,    // [rows, D]
    const float* __restrict__ k,    // [rows*4, D]
    const float* __restrict__ v,    // [rows*4, D]
    const float* __restrict__ lw,   // [D]
    const float* __restrict__ lb,   // [D]
    float* __restrict__ out,        // [rows, D]
    int rows)
{
    const int  tid  = threadIdx.x;
    const int  lane = tid & 63;
    const int  wid  = tid >> 6;
    const int  sl   = lane * 4;                    // element slot within each 256-chunk
    const long gw   = (long)blockIdx.x * NW + wid; // global wave id
    long r = gw * NRW;

    // ---- row-invariant: w,b resident (32 VGPRs) + their 3 reductions, once ----
    f32x4 wv[4], bv[4];
#pragma unroll
    for (int i = 0; i < 4; i++) {
        wv[i] = *(const f32x4*)(lw + i * 256 + sl);
        bv[i] = *(const f32x4*)(lb + i * 256 + sl);
    }
    f32x4 aw2 = {0.f, 0.f, 0.f, 0.f}, awb = {0.f, 0.f, 0.f, 0.f}, ab2 = {0.f, 0.f, 0.f, 0.f};
#pragma unroll
    for (int i = 0; i < 4; i++) {
        aw2 = vfma(wv[i], wv[i], aw2);
        awb = vfma(wv[i], bv[i], awb);
        ab2 = vfma(bv[i], bv[i], ab2);
    }
    const float Sw2 = wave_sum(hsum(aw2));
    const float Swb = wave_sum(hsum(awb));
    const float Sb2 = wave_sum(hsum(ab2));
    const float invD = 1.0f / (float)D;

#pragma unroll 1
    for (int rr = 0; rr < NRW; rr++, r++) {
        if (r >= rows) break;
        const float* qp = q + r * (long)D;
        const float* kp = k + r * (4L * D);
        const float* vp = v + r * (4L * D);

        // ---- issue ALL 36 dwordx4 loads of the row, back to back ----
        f32x4 qv[4], kv[4][4], vv[4][4];
#pragma unroll
        for (int i = 0; i < 4; i++) qv[i] = *(const f32x4*)(qp + i * 256 + sl);
#pragma unroll
        for (int f = 0; f < 4; f++)
#pragma unroll
            for (int i = 0; i < 4; i++)
                kv[f][i] = *(const f32x4*)(kp + f * D + i * 256 + sl);
#pragma unroll
        for (int f = 0; f < 4; f++)
#pragma unroll
            for (int i = 0; i < 4; i++)
                vv[f][i] = *(const f32x4*)(vp + f * D + i * 256 + sl);

        // ---- pin the batch: no load may sink below here ----
        PIN16(kv);
        PIN16(vv);
        PIN4(qv);
        __builtin_amdgcn_sched_barrier(0);

        // ---- per-lane partials (single pass over resident registers) ----
        f32x4 qw[4];
#pragma unroll
        for (int i = 0; i < 4; i++) qw[i] = vmul(qv[i], wv[i]);   // q*w, reused 6x

        // k partials first so the 64 k-regs die early.
        float pSk[4], pSkk[4], pSkw2[4], pSkwb[4], pA[4];
#pragma unroll
        for (int f = 0; f < 4; f++) {
            f32x4 s = {0.f,0.f,0.f,0.f}, ss = s, sw2a = s, swba = s, sA = s;
#pragma unroll
            for (int i = 0; i < 4; i++) {
                f32x4 kk = kv[f][i];
                s    = vadd(s, kk);
                ss   = vfma(kk, kk, ss);
                f32x4 t = vmul(kk, wv[i]);
                sw2a = vfma(t, wv[i], sw2a);
                swba = vfma(t, bv[i], swba);
                sA   = vfma(t, qw[i], sA);
            }
            pSk[f] = hsum(s); pSkk[f] = hsum(ss);
            pSkw2[f] = hsum(sw2a); pSkwb[f] = hsum(swba); pA[f] = hsum(sA);
        }

        // q partials: Sq, Sqq, Sqw2 = Sum q*w*w, Sqwb = Sum q*w*b
        f32x4 a0 = {0.f,0.f,0.f,0.f}, a1 = a0, a2 = a0, a3 = a0;
#pragma unroll
        for (int i = 0; i < 4; i++) {
            a0 = vadd(a0, qv[i]);
            a1 = vfma(qv[i], qv[i], a1);
            a2 = vfma(qw[i], wv[i], a2);
            a3 = vfma(qw[i], bv[i], a3);
        }
        float pSq = hsum(a0), pSqq = hsum(a1), pSqw2 = hsum(a2), pSqwb = hsum(a3);

        // v partials: Sv_f, Svv_f
        float pSv[4], pSvv[4];
#pragma unroll
        for (int f = 0; f < 4; f++) {
            f32x4 s = {0.f,0.f,0.f,0.f}, ss = s;
#pragma unroll
            for (int i = 0; i < 4; i++) {
                s  = vadd(s, vv[f][i]);
                ss = vfma(vv[f][i], vv[f][i], ss);
            }
            pSv[f] = hsum(s); pSvv[f] = hsum(ss);
        }

        // ---- one round of 32 in-wave reductions (DPP, no barrier) ----
        const float Sq   = wave_sum(pSq);
        const float Sqq  = wave_sum(pSqq);
        const float Sqw2 = wave_sum(pSqw2);
        const float Sqwb = wave_sum(pSqwb);
        float Sk[4], Skk[4], Skw2[4], Skwb[4], A[4], Sv[4], Svv[4];
#pragma unroll
        for (int f = 0; f < 4; f++) {
            Sk[f]   = wave_sum(pSk[f]);
            Skk[f]  = wave_sum(pSkk[f]);
            Skw2[f] = wave_sum(pSkw2[f]);
            Skwb[f] = wave_sum(pSkwb[f]);
            A[f]    = wave_sum(pA[f]);
            Sv[f]   = wave_sum(pSv[f]);
            Svv[f]  = wave_sum(pSvv[f]);
        }

        // ---- scalar stats + expanded dot(qn, kn_f) ----
        const float mu_q = Sq * invD;
        const float rs_q = rsqrtf(fmaf(-mu_q, mu_q, Sqq * invD) + EPS);
        const float qlin = rs_q * (Sqwb - mu_q * Swb);   // rs_q * Sum (q-mu_q) w b
        float dp[4], rs_v[4], cv[4];
#pragma unroll
        for (int f = 0; f < 4; f++) {
            const float mu_k = Sk[f] * invD;
            const float rs_k = rsqrtf(fmaf(-mu_k, mu_k, Skk[f] * invD) + EPS);
            const float mu_v = Sv[f] * invD;
            const float rv   = rsqrtf(fmaf(-mu_v, mu_v, Svv[f] * invD) + EPS);
            const float cross = A[f] - mu_k * Sqw2 - mu_q * Skw2[f] + mu_q * mu_k * Sw2;
            dp[f] = rs_q * rs_k * cross + qlin + rs_k * (Skwb[f] - mu_k * Swb) + Sb2;
            rs_v[f] = rv;
            cv[f]   = -mu_v * rv;
        }

        // ---- epilogue from resident q,v: out = q + sum_f dp_f * LN(v_f) ----
#pragma unroll
        for (int i = 0; i < 4; i++) {
            f32x4 acc = qv[i];
#pragma unroll
            for (int f = 0; f < 4; f++) {
                f32x4 t  = vfma_ss(vv[f][i], rs_v[f], cv[f]);  // (v - mu_v)*rs_v
                f32x4 vn = vfma(t, wv[i], bv[i]);              // * w + b
                acc = vfma_sv(dp[f], vn, acc);                 // += dp * vn
            }
            *(f32x4*)(out + r * (long)D + i * 256 + sl) = acc;
        }
    }
}

extern "C" void kernel_launch(void* const* d_in, const int* in_sizes, int n_in,
                              void* d_out, int out_size, void* d_ws, size_t ws_size,
                              hipStream_t stream) {
    const float* q  = (const float*)d_in[0];
    const float* k  = (const float*)d_in[1];
    const float* v  = (const float*)d_in[2];
    const float* lw = (const float*)d_in[3];
    const float* lb = (const float*)d_in[4];
    float* out = (float*)d_out;

    const int rows = in_sizes[0] / D;                     // B*Sq = 8192
    const int grid = (rows + NW * NRW - 1) / (NW * NRW);  // 512 = 2 blocks/CU
    attn_ds_kernel<<<dim3(grid), dim3(BLOCK), 0, stream>>>(q, k, v, lw, lb, out, rows);
}

// Round 5
// 311.596 us; speedup vs baseline: 1.0197x; 1.0197x over previous
//
#include <hip/hip_runtime.h>

// AttentionSampling: out[b,s,:] = q[b,s,:] + sum_f dot(LN(q)[b,s,:], LN(k)[b,4s+f,:]) * LN(v)[b,4s+f,:]
// B=4, Sq=2048, Skv=8192, D=1024, fp32.
//
// R9 = R8 resubmit (R8 bench died at container acquisition, no kernel data) with
// defensive hardening: combined vmcnt/lgkmcnt drain before LDS reads, and the
// row guard wraps the body instead of early-return.
//
// Design: R6 (register batch -> RA sank loads) and R7 (pinned batch -> RA
// spilled, +45% WRITE_SIZE) prove the RA dismantles >100-VGPR load batches.
// R4 proved global_load_lds (0 dest VGPRs) reliably keeps 16-36KB/wave in
// flight; its cost was the block-wide barrier convoy. Combine:
//   - V via global_load_lds into WAVE-PRIVATE LDS (16KB/wave) -> no s_barrier,
//     only the wave's own counted wait placed after the whole K phase.
//   - K streams through a 2-row register window (32 VGPR) with the expanded-dot
//     single-pass math (harness-verified in R6/R7):
//       dp_f = rs_q*rs_k*(A_f - mu_k*Sqw2 - mu_q*Skw2_f + mu_q*mu_k*Sw2)
//            + rs_q*(Sqwb - mu_q*Swb) + rs_k*(Skwb_f - mu_k*Swb) + Sb2
//   - V stats + epilogue read V twice from LDS (stride-16B ds_read_b128,
//     2-way bank alias = free per m136).
// One wave per row, 2048 blocks, 8 waves/CU -> ~170KB outstanding/CU >> ~25KB
// Little's-law requirement for full HBM rate.

typedef float f32x4 __attribute__((ext_vector_type(4)));

constexpr int D     = 1024;
constexpr int BLOCK = 256;
constexpr int NW    = BLOCK / 64;   // 4 waves per block, 1 row each
constexpr float EPS = 1e-5f;

#define GLOBAL_AS const __attribute__((address_space(1))) void*
#define LDS_AS __attribute__((address_space(3))) void*

template<int CTRL>
__device__ __forceinline__ float dpp_add(float x) {
    int xi = __builtin_bit_cast(int, x);
    int yi = __builtin_amdgcn_update_dpp(0, xi, CTRL, 0xF, 0xF, true);
    return x + __builtin_bit_cast(float, yi);
}

// Full wave64 sum on the VALU pipe; broadcast via readlane. No LDS, no barrier.
__device__ __forceinline__ float wave_sum(float x) {
    x = dpp_add<0x111>(x);   // row_shr:1
    x = dpp_add<0x112>(x);   // row_shr:2
    x = dpp_add<0x114>(x);   // row_shr:4
    x = dpp_add<0x118>(x);   // row_shr:8
    x = dpp_add<0x142>(x);   // row_bcast:15
    x = dpp_add<0x143>(x);   // row_bcast:31 -> lane 63 holds wave sum
    return __builtin_bit_cast(float, __builtin_amdgcn_readlane(__builtin_bit_cast(int, x), 63));
}

__device__ __forceinline__ f32x4 vadd(f32x4 a, f32x4 b) {
    f32x4 r;
#pragma unroll
    for (int j = 0; j < 4; j++) r[j] = a[j] + b[j];
    return r;
}
__device__ __forceinline__ f32x4 vmul(f32x4 a, f32x4 b) {
    f32x4 r;
#pragma unroll
    for (int j = 0; j < 4; j++) r[j] = a[j] * b[j];
    return r;
}
__device__ __forceinline__ f32x4 vfma(f32x4 a, f32x4 b, f32x4 c) {
    f32x4 r;
#pragma unroll
    for (int j = 0; j < 4; j++) r[j] = fmaf(a[j], b[j], c[j]);
    return r;
}
__device__ __forceinline__ f32x4 vfma_ss(f32x4 a, float s, float c) {
    f32x4 r;
#pragma unroll
    for (int j = 0; j < 4; j++) r[j] = fmaf(a[j], s, c);
    return r;
}
__device__ __forceinline__ f32x4 vfma_sv(float s, f32x4 b, f32x4 c) {
    f32x4 r;
#pragma unroll
    for (int j = 0; j < 4; j++) r[j] = fmaf(s, b[j], c[j]);
    return r;
}
__device__ __forceinline__ float hsum(f32x4 a) { return (a[0] + a[1]) + (a[2] + a[3]); }

// Pin a 4-vector window: loads feeding these regs cannot sink below this point.
#define PINW(A) asm volatile("" :: "v"(A[0]), "v"(A[1]), "v"(A[2]), "v"(A[3]))

__global__ __launch_bounds__(BLOCK, 2) void attn_ds_kernel(
    const float* __restrict__ q,    // [rows, D]
    const float* __restrict__ k,    // [rows*4, D]
    const float* __restrict__ v,    // [rows*4, D]
    const float* __restrict__ lw,   // [D]
    const float* __restrict__ lb,   // [D]
    float* __restrict__ out,        // [rows, D]
    int rows)
{
    __shared__ float v_lds[NW][4 * D];   // 16KB per wave, wave-private -> no barrier

    const int  tid  = threadIdx.x;
    const int  lane = tid & 63;
    const int  wid  = tid >> 6;
    const int  sl   = lane * 4;                     // 16B slot within each 1KB chunk
    const long r    = (long)blockIdx.x * NW + wid;  // one row per wave

    if (r < rows) {
        const float* qp = q + r * (long)D;
        const float* kp = k + r * (4L * D);
        const float* vp = v + r * (4L * D);
        float* vl = &v_lds[wid][0];

        // ---- 1. fire-and-forget V DMA: 16 x 1KB chunks, zero dest VGPRs ----
#pragma unroll
        for (int c = 0; c < 16; c++)
            __builtin_amdgcn_global_load_lds((GLOBAL_AS)(vp + c * 256 + sl),
                                             (LDS_AS)(vl + c * 256), 16, 0, 0);

        // ---- 2. w,b resident + their 3 invariant reductions ----
        f32x4 wv[4], bv[4];
#pragma unroll
        for (int i = 0; i < 4; i++) {
            wv[i] = *(const f32x4*)(lw + i * 256 + sl);
            bv[i] = *(const f32x4*)(lb + i * 256 + sl);
        }
        f32x4 aw2 = {0.f,0.f,0.f,0.f}, awb = aw2, ab2 = aw2;
#pragma unroll
        for (int i = 0; i < 4; i++) {
            aw2 = vfma(wv[i], wv[i], aw2);
            awb = vfma(wv[i], bv[i], awb);
            ab2 = vfma(bv[i], bv[i], ab2);
        }
        const float Sw2 = wave_sum(hsum(aw2));
        const float Swb = wave_sum(hsum(awb));
        const float Sb2 = wave_sum(hsum(ab2));
        const float invD = 1.0f / (float)D;

        // ---- 3. q resident + partials ----
        f32x4 qv[4], qw[4];
#pragma unroll
        for (int i = 0; i < 4; i++) qv[i] = *(const f32x4*)(qp + i * 256 + sl);
        PINW(qv);
        f32x4 a0 = {0.f,0.f,0.f,0.f}, a1 = a0, a2 = a0, a3 = a0;
#pragma unroll
        for (int i = 0; i < 4; i++) {
            qw[i] = vmul(qv[i], wv[i]);           // q*w, reused in A_f
            a0 = vadd(a0, qv[i]);
            a1 = vfma(qv[i], qv[i], a1);
            a2 = vfma(qw[i], wv[i], a2);
            a3 = vfma(qw[i], bv[i], a3);
        }
        const float pSq = hsum(a0), pSqq = hsum(a1), pSqw2 = hsum(a2), pSqwb = hsum(a3);

        // ---- 4. K: single streaming pass, 2-row register window (32 VGPR) ----
        float pSk[4], pSkk[4], pSkw2[4], pSkwb[4], pA[4];
        f32x4 kw0[4], kw1[4];
#pragma unroll
        for (int i = 0; i < 4; i++) kw0[i] = *(const f32x4*)(kp + 0 * D + i * 256 + sl);
#pragma unroll
        for (int i = 0; i < 4; i++) kw1[i] = *(const f32x4*)(kp + 1 * D + i * 256 + sl);
        PINW(kw0); PINW(kw1);
        __builtin_amdgcn_sched_barrier(0);

#define PROCK(f, KK) { \
        f32x4 s = {0.f,0.f,0.f,0.f}, ss = s, sw2a = s, swba = s, sA = s; \
        _Pragma("unroll") \
        for (int i = 0; i < 4; i++) { \
            f32x4 kk = KK[i]; \
            s    = vadd(s, kk); \
            ss   = vfma(kk, kk, ss); \
            f32x4 t = vmul(kk, wv[i]); \
            sw2a = vfma(t, wv[i], sw2a); \
            swba = vfma(t, bv[i], swba); \
            sA   = vfma(t, qw[i], sA); \
        } \
        pSk[f] = hsum(s); pSkk[f] = hsum(ss); \
        pSkw2[f] = hsum(sw2a); pSkwb[f] = hsum(swba); pA[f] = hsum(sA); }

        PROCK(0, kw0);
#pragma unroll
        for (int i = 0; i < 4; i++) kw0[i] = *(const f32x4*)(kp + 2 * D + i * 256 + sl);
        PINW(kw0);
        __builtin_amdgcn_sched_barrier(0);

        PROCK(1, kw1);
#pragma unroll
        for (int i = 0; i < 4; i++) kw1[i] = *(const f32x4*)(kp + 3 * D + i * 256 + sl);
        PINW(kw1);
        __builtin_amdgcn_sched_barrier(0);

        PROCK(2, kw0);
        PROCK(3, kw1);
#undef PROCK

        // ---- 5. V stats from LDS (wave-private: wait own counters, NO barrier) ----
        asm volatile("s_waitcnt vmcnt(0) lgkmcnt(0)" ::: "memory");
        __builtin_amdgcn_sched_barrier(0);
        float pSv[4], pSvv[4];
#pragma unroll
        for (int f = 0; f < 4; f++) {
            f32x4 s = {0.f,0.f,0.f,0.f}, ss = s;
#pragma unroll
            for (int i = 0; i < 4; i++) {
                f32x4 vvif = *(const f32x4*)(vl + f * D + i * 256 + sl);
                s  = vadd(s, vvif);
                ss = vfma(vvif, vvif, ss);
            }
            pSv[f] = hsum(s); pSvv[f] = hsum(ss);
        }

        // ---- 6. one DPP reduction round (32 sums), no barrier ----
        const float Sq   = wave_sum(pSq);
        const float Sqq  = wave_sum(pSqq);
        const float Sqw2 = wave_sum(pSqw2);
        const float Sqwb = wave_sum(pSqwb);
        float Sk[4], Skk[4], Skw2[4], Skwb[4], A[4], Sv[4], Svv[4];
#pragma unroll
        for (int f = 0; f < 4; f++) {
            Sk[f]   = wave_sum(pSk[f]);
            Skk[f]  = wave_sum(pSkk[f]);
            Skw2[f] = wave_sum(pSkw2[f]);
            Skwb[f] = wave_sum(pSkwb[f]);
            A[f]    = wave_sum(pA[f]);
            Sv[f]   = wave_sum(pSv[f]);
            Svv[f]  = wave_sum(pSvv[f]);
        }

        // ---- 7. scalar stats + expanded dot(qn, kn_f) (R6/R7 math, verified) ----
        const float mu_q = Sq * invD;
        const float rs_q = rsqrtf(fmaf(-mu_q, mu_q, Sqq * invD) + EPS);
        const float qlin = rs_q * (Sqwb - mu_q * Swb);
        float dp[4], rs_v[4], cv[4];
#pragma unroll
        for (int f = 0; f < 4; f++) {
            const float mu_k = Sk[f] * invD;
            const float rs_k = rsqrtf(fmaf(-mu_k, mu_k, Skk[f] * invD) + EPS);
            const float mu_v = Sv[f] * invD;
            const float rv   = rsqrtf(fmaf(-mu_v, mu_v, Svv[f] * invD) + EPS);
            const float cross = A[f] - mu_k * Sqw2 - mu_q * Skw2[f] + mu_q * mu_k * Sw2;
            dp[f] = rs_q * rs_k * cross + qlin + rs_k * (Skwb[f] - mu_k * Swb) + Sb2;
            rs_v[f] = rv;
            cv[f]   = -mu_v * rv;
        }

        // ---- 8. epilogue: re-read V from LDS, out = q + sum_f dp_f * LN(v_f) ----
#pragma unroll
        for (int i = 0; i < 4; i++) {
            f32x4 acc = qv[i];
#pragma unroll
            for (int f = 0; f < 4; f++) {
                f32x4 vvif = *(const f32x4*)(vl + f * D + i * 256 + sl);
                f32x4 t  = vfma_ss(vvif, rs_v[f], cv[f]);   // (v - mu_v)*rs_v
                f32x4 vn = vfma(t, wv[i], bv[i]);           // * w + b
                acc = vfma_sv(dp[f], vn, acc);              // += dp * vn
            }
            *(f32x4*)(out + r * (long)D + i * 256 + sl) = acc;
        }
    }
}

extern "C" void kernel_launch(void* const* d_in, const int* in_sizes, int n_in,
                              void* d_out, int out_size, void* d_ws, size_t ws_size,
                              hipStream_t stream) {
    const float* q  = (const float*)d_in[0];
    const float* k  = (const float*)d_in[1];
    const float* v  = (const float*)d_in[2];
    const float* lw = (const float*)d_in[3];
    const float* lb = (const float*)d_in[4];
    float* out = (float*)d_out;

    const int rows = in_sizes[0] / D;            // B*Sq = 8192
    const int grid = (rows + NW - 1) / NW;       // 2048 blocks, 1 row per wave
    attn_ds_kernel<<<dim3(grid), dim3(BLOCK), 0, stream>>>(q, k, v, lw, lb, out, rows);
}